// Round 7
// baseline (189.060 us; speedup 1.0000x reference)
//
#include <hip/hip_runtime.h>
#include <hip/hip_bf16.h>

// Shapes: B=8, Q=1, T=2048, H=512, V=32000
#define Hdim 512
#define Bdim 8
#define Tdim 2048
#define Vdim 32000
#define OUTW (Vdim + Tdim)        // 34048
#define DEC_TILES (Vdim / 128)    // 250
#define REP_TILES ((Bdim * Tdim) / 128)  // 128
#define NTILES (DEC_TILES + REP_TILES)   // 378

typedef __attribute__((ext_vector_type(8))) short short8;
typedef __attribute__((ext_vector_type(16))) float f32x16;

__device__ __forceinline__ unsigned packbf2(float a, float b) {
    __hip_bfloat162 h = __float22bfloat162_rn(make_float2(a, b));  // a -> low 16
    union { __hip_bfloat162 h; unsigned u; } c; c.h = h;
    return c.u;
}

union U8 { unsigned u[4]; short8 s; };
__device__ __forceinline__ short8 cvt8(const float4 f0, const float4 f1) {
    U8 r;
    r.u[0] = packbf2(f0.x, f0.y); r.u[1] = packbf2(f0.z, f0.w);
    r.u[2] = packbf2(f1.x, f1.y); r.u[3] = packbf2(f1.z, f1.w);
    return r.s;
}

// ---------------- prep: w1t -> bf16 [n][k] + qp, one tiny launch ----------------
#define WT_BLOCKS 128                  // 512x512 elems, 8 per thread
#define QP_BLOCKS (Bdim * Hdim / 4)    // 1024 blocks of 4 waves

__global__ __launch_bounds__(256) void prep_kernel(
    const float* __restrict__ w1, const float* __restrict__ x,
    const float* __restrict__ b1,
    unsigned short* __restrict__ wt, float* __restrict__ qp)
{
    const int bid = blockIdx.x;
    if (bid < WT_BLOCKS) {
        // wt[n][kk] = bf16(w1[n*1024 + 512 + kk])
        const int i = bid * 256 + threadIdx.x;   // 8-elem group index
        const int n = i >> 6;
        const int kk = (i & 63) * 8;
        const float4* s = (const float4*)(w1 + (size_t)n * 1024 + 512 + kk);
        const float4 v0 = s[0], v1 = s[1];
        uint4 o;
        o.x = packbf2(v0.x, v0.y); o.y = packbf2(v0.z, v0.w);
        o.z = packbf2(v1.x, v1.y); o.w = packbf2(v1.z, v1.w);
        ((uint4*)wt)[i] = o;
    } else {
        // qp[b,k] = x[b,:].w1q[k,:] + b1[k], one wave per (b,k)
        const int widx = (bid - WT_BLOCKS) * 4 + (threadIdx.x >> 6);
        const int lane = threadIdx.x & 63;
        const int b = widx >> 9, k = widx & 511;
        const float4* xr = (const float4*)(x + b * Hdim);
        const float4* wr = (const float4*)(w1 + (size_t)k * 1024);
        float4 x0 = xr[lane * 2], x1 = xr[lane * 2 + 1];
        float4 w0 = wr[lane * 2], w1v = wr[lane * 2 + 1];
        float s = x0.x * w0.x + x0.y * w0.y + x0.z * w0.z + x0.w * w0.w
                + x1.x * w1v.x + x1.y * w1v.y + x1.z * w1v.z + x1.w * w1v.w;
#pragma unroll
        for (int off = 32; off > 0; off >>= 1) s += __shfl_down(s, off);
        if (lane == 0) qp[b * Hdim + k] = s + b1[k];
    }
}

// ---------------- fused MFMA GEMM + epilogue -> partial sums ----------------
// Grid 1536 (48 groups x 32): mt = (b>>5)*8 + (b&7), chunk = (b>>3)&3 so the 4
// chunk-partners of one mt share blockIdx%8 (same XCD -> shared L2 A-tile).
// MFMA operands SWAPPED (mfma(W,A)): acc rows = n, acc cols = output row; the
// relu(P+qp).w2 n-reduction is in-lane over acc slots + one shfl_xor(32).
// Round-7 structure (round-6's hand-counted vmcnt RACED -> reverted to
// compiler-managed waits):
//  * A is reg-staged and converted fp32->bf16 ONCE at staging; LDS tiles are
//    bf16 [2][64][64] for both A and W (32 KB total) -> 4 blocks/CU, and the
//    inner loop is pure {8 ds_read_b128 + 16 MFMA} (no cvt on MFMA path).
//  * per K-step: COMPUTE(cur); CVT_WRITE(cur^1) [tile t+1]; GLOAD [tile t+2];
//    { lgkmcnt(0); s_barrier }.  Staging-load vmcnt waits are inserted by the
//    compiler at the cvt's data dependence (deterministic); the barrier drains
//    only LDS ops, so global loads stay in flight across it (m201 pair).
__global__ __launch_bounds__(256, 4) void gemm_kernel(
    const float* __restrict__ Adec,            // 32000 x 512 fp32 (original)
    const float* __restrict__ Atgt,            // 16384 x 512 fp32 (original)
    const unsigned short* __restrict__ Wt,     // 512 x 512 bf16 (w1t [n][k])
    const float* __restrict__ qp,              // 8 x 512 fp32
    const float* __restrict__ w2,              // 512 fp32
    float* __restrict__ Pd,                    // 8 x 8 x 32000 fp32 partials
    float* __restrict__ Pr)                    // 8 x 16384 fp32 partials
{
    // A/W: bf16 tile 128 x 32k packed 2 rows/LDS-row: elem(row,k) at
    // [row&63][(row>>6)*32 + k]; row = 8 x 16B slots, phys slot = logical ^ (rr&7).
    __shared__ union {
        struct { unsigned short A[2][64][64]; unsigned short W[2][64][64]; } g;  // 32 KB
        struct { float qT[8][128]; float w2c[128]; } e;
    } u;

    const int tid  = threadIdx.x;
    const int lane = tid & 63;
    const int w    = tid >> 6;

    const int b = blockIdx.x;
    const int mt = (b >> 5) * 8 + (b & 7);
    if (mt >= NTILES) return;
    const int chunk = (b >> 3) & 3;
    const int n0 = chunk << 7;
    const bool is_dec = (mt < DEC_TILES);
    const int m0 = (is_dec ? mt : mt - DEC_TILES) << 7;
    const float* __restrict__ Af = is_dec ? Adec : Atgt;

    // ---- staging assignment: thread -> (row sr2 = tid>>1, k-half sh = tid&1) ----
    // A: 64B (16 fp32), W: 32B (16 bf16) per thread per tile, consecutive.
    const int sr2 = tid >> 1;
    const int sh  = tid & 1;
    const float* gAq = Af + (size_t)(m0 + sr2) * 512 + sh * 16;
    const short* gWq = (const short*)Wt + (size_t)(n0 + sr2) * 512 + sh * 16;
    // LDS write slots: rr = sr2&63, logical slots {sb, sb+1}, sb = (sr2>>6)*4 + sh*2
    const int wrr = sr2 & 63;
    const int wsb = ((sr2 >> 6) << 2) + (sh << 1);
    const int wp0 = ((wsb)     ^ (wrr & 7)) << 3;   // short offset
    const int wp1 = ((wsb + 1) ^ (wrr & 7)) << 3;

    float4 rA0, rA1, rA2, rA3;
    short8 rW0, rW1;

#define GLOAD() do {                                                          \
        rA0 = *(const float4*)(gAq);      rA1 = *(const float4*)(gAq + 4);    \
        rA2 = *(const float4*)(gAq + 8);  rA3 = *(const float4*)(gAq + 12);   \
        rW0 = *(const short8*)(gWq);      rW1 = *(const short8*)(gWq + 8);    \
        gAq += 32; gWq += 32;                                                 \
    } while (0)

#define CVT_WRITE(bb) do {                                                    \
        *(short8*)&u.g.A[bb][wrr][wp0] = cvt8(rA0, rA1);                      \
        *(short8*)&u.g.A[bb][wrr][wp1] = cvt8(rA2, rA3);                      \
        *(short8*)&u.g.W[bb][wrr][wp0] = rW0;                                 \
        *(short8*)&u.g.W[bb][wrr][wp1] = rW1;                                 \
    } while (0)

    // barrier that drains LDS ops only (global staging loads stay in flight)
#define BAR_LK() do {                                                         \
        asm volatile("s_waitcnt lgkmcnt(0)" ::: "memory");                    \
        __builtin_amdgcn_s_barrier();                                         \
        __builtin_amdgcn_sched_barrier(0);                                    \
    } while (0)

    f32x16 acc00, acc01, acc10, acc11;
#pragma unroll
    for (int i = 0; i < 16; ++i) { acc00[i] = 0.f; acc01[i] = 0.f; acc10[i] = 0.f; acc11[i] = 0.f; }

    const int wm  = (w & 1) << 6;     // output-row offset of this wave
    const int wn  = (w >> 1) << 6;    // n offset of this wave (within chunk)
    const int l31 = lane & 31;
    const int kh  = lane >> 5;
    const int rx7 = l31 & 7;          // (rr&7) for reads; rows l31 and l31+32 share it
    const int ha  = wm >> 6;          // A packed-half
    const int hw  = wn >> 6;          // W packed-half

#define COMPUTE(bb) do {                                                      \
        _Pragma("unroll")                                                     \
        for (int s = 0; s < 2; ++s) {                                         \
            const int g  = s * 2 + kh;                                        \
            const int soA = (((ha << 2) + g) ^ rx7) << 3;                     \
            const int soW = (((hw << 2) + g) ^ rx7) << 3;                     \
            const short8 a0 = *(const short8*)&u.g.A[bb][l31][soA];           \
            const short8 a1 = *(const short8*)&u.g.A[bb][l31 + 32][soA];      \
            const short8 b0 = *(const short8*)&u.g.W[bb][l31][soW];           \
            const short8 b1 = *(const short8*)&u.g.W[bb][l31 + 32][soW];      \
            acc00 = __builtin_amdgcn_mfma_f32_32x32x16_bf16(b0, a0, acc00, 0, 0, 0); \
            acc01 = __builtin_amdgcn_mfma_f32_32x32x16_bf16(b0, a1, acc01, 0, 0, 0); \
            acc10 = __builtin_amdgcn_mfma_f32_32x32x16_bf16(b1, a0, acc10, 0, 0, 0); \
            acc11 = __builtin_amdgcn_mfma_f32_32x32x16_bf16(b1, a1, acc11, 0, 0, 0); \
        }                                                                     \
    } while (0)

    // prologue: tile 0 -> regs -> buf0; issue tile 1 loads; publish buf0.
    GLOAD();              // tile 0
    CVT_WRITE(0);         // waits tile-0 loads via data dep
    GLOAD();              // tile 1 (in flight across barrier + first COMPUTE)
    BAR_LK();

    int cur = 0;
    for (int t = 0; t < 16; ++t) {
        COMPUTE(cur);                 // tile t from buf[cur]
        if (t < 15) {
            CVT_WRITE(cur ^ 1);       // tile t+1 regs -> buf[cur^1] (vmcnt dep here)
            if (t < 14) GLOAD();      // tile t+2 -> regs; hides under barrier+COMPUTE
        }
        BAR_LK();                     // publish writes; all reads of buf[cur] drained
        cur ^= 1;
    }

#undef COMPUTE
#undef GLOAD
#undef CVT_WRITE
#undef BAR_LK

    // ---------------- fused epilogue ----------------
    // acc{X}{Y}[r]: n = wn + 32*X + ra2(r,kh), vrow = wm + 32*Y + l31
    // with r = run*4 + j: ra2 = j + 8*run + 4*kh  -> n runs are float4-contiguous.
    // (C/D layout verified m74/m101: col=lane&31, row=(r&3)+8*(r>>2)+4*(lane>>5))
    {
        const int qb = tid >> 5;              // 0..7
        const int qn = (tid & 31) << 2;       // 0..124
        *(float4*)&u.e.qT[qb][qn] = *(const float4*)&qp[qb * Hdim + n0 + qn];
        if (tid < 32) *(float4*)&u.e.w2c[tid << 2] = *(const float4*)&w2[n0 + (tid << 2)];
    }
    __syncthreads();

    const int kh4 = kh << 2;
    const int slice = (chunk << 1) + (wn >> 6);   // 0..7: (chunk, n-half) id

    // w2 fragments in regs (statically indexed -> 8 float4 = 32 VGPRs)
    float4 wvA[4], wvB[4];
#pragma unroll
    for (int run = 0; run < 4; ++run) {
        wvA[run] = *(const float4*)&u.e.w2c[wn + run * 8 + kh4];
        wvB[run] = *(const float4*)&u.e.w2c[wn + 32 + run * 8 + kh4];
    }

    // per-b2 scalar partial pair: p0 = row wm+l31, p1 = row wm+32+l31
#define EPI_PAIR(QROW, T0, T1) do {                                          \
        float _p0 = 0.f, _p1 = 0.f;                                          \
        _Pragma("unroll")                                                    \
        for (int run = 0; run < 4; ++run) {                                  \
            const float4 q0 = *(const float4*)((QROW) + wn + run * 8 + kh4); \
            const float4 q1 = *(const float4*)((QROW) + wn + 32 + run * 8 + kh4); \
            const float4 wA = wvA[run], wB = wvB[run];                       \
            _p0 += fmaxf(acc00[run * 4 + 0] + q0.x, 0.f) * wA.x;             \
            _p1 += fmaxf(acc01[run * 4 + 0] + q0.x, 0.f) * wA.x;             \
            _p0 += fmaxf(acc10[run * 4 + 0] + q1.x, 0.f) * wB.x;             \
            _p1 += fmaxf(acc11[run * 4 + 0] + q1.x, 0.f) * wB.x;             \
            _p0 += fmaxf(acc00[run * 4 + 1] + q0.y, 0.f) * wA.y;             \
            _p1 += fmaxf(acc01[run * 4 + 1] + q0.y, 0.f) * wA.y;             \
            _p0 += fmaxf(acc10[run * 4 + 1] + q1.y, 0.f) * wB.y;             \
            _p1 += fmaxf(acc11[run * 4 + 1] + q1.y, 0.f) * wB.y;             \
            _p0 += fmaxf(acc00[run * 4 + 2] + q0.z, 0.f) * wA.z;             \
            _p1 += fmaxf(acc01[run * 4 + 2] + q0.z, 0.f) * wA.z;             \
            _p0 += fmaxf(acc10[run * 4 + 2] + q1.z, 0.f) * wB.z;             \
            _p1 += fmaxf(acc11[run * 4 + 2] + q1.z, 0.f) * wB.z;             \
            _p0 += fmaxf(acc00[run * 4 + 3] + q0.w, 0.f) * wA.w;             \
            _p1 += fmaxf(acc01[run * 4 + 3] + q0.w, 0.f) * wA.w;             \
            _p0 += fmaxf(acc10[run * 4 + 3] + q1.w, 0.f) * wB.w;             \
            _p1 += fmaxf(acc11[run * 4 + 3] + q1.w, 0.f) * wB.w;             \
        }                                                                    \
        T0 = _p0 + __shfl_xor(_p0, 32);                                      \
        T1 = _p1 + __shfl_xor(_p1, 32);                                      \
    } while (0)

    if (is_dec) {
#pragma unroll
        for (int b2 = 0; b2 < 8; ++b2) {
            float t0, t1;
            EPI_PAIR(&u.e.qT[b2][0], t0, t1);
            if (kh == 0) {
                float* o = Pd + ((size_t)slice * 8 + b2) * Vdim + m0 + wm;
                o[l31]      = t0;
                o[32 + l31] = t1;
            }
        }
    } else {
        const int bfix = m0 >> 11;          // 128-row tile never crosses a batch
        float t0, t1;
        EPI_PAIR(&u.e.qT[bfix][0], t0, t1);
        if (kh == 0) {
            float* o = Pr + (size_t)slice * (Bdim * Tdim) + m0 + wm;
            o[l31]      = t0;   // raw sums; mask applied in reduce
            o[32 + l31] = t1;
        }
    }
#undef EPI_PAIR
}

// ---------------- reduce: sum the 8 (chunk, n-half) partial slices ----------------
#define RED_DEC_BLOCKS (Bdim * Vdim / 4 / 256)        // 250 (float4 granularity)
#define RED_REP_BLOCKS (Bdim * Tdim / 4 / 256)        // 16

__global__ __launch_bounds__(256) void reduce_kernel(
    const float* __restrict__ Pd, const float* __restrict__ Pr,
    const float* __restrict__ mask, float* __restrict__ out)
{
    const int blk = blockIdx.x;
    if (blk < RED_DEC_BLOCKS) {
        const int i4 = blk * 256 + threadIdx.x;          // float4 idx into [8][8000]
        const int b  = i4 / (Vdim / 4);
        const int v4 = i4 - b * (Vdim / 4);
        const float4* p = (const float4*)Pd + (size_t)b * (Vdim / 4) + v4;
        const size_t cs = (size_t)Bdim * (Vdim / 4);     // slice stride in float4
        float4 s = p[0];
#pragma unroll
        for (int c = 1; c < 8; ++c) {
            const float4 v = p[c * cs];
            s.x += v.x; s.y += v.y; s.z += v.z; s.w += v.w;
        }
        *(float4*)(out + (size_t)b * OUTW + v4 * 4) = s;
    } else {
        const int i4 = (blk - RED_DEC_BLOCKS) * 256 + threadIdx.x;   // 0..4095
        const int rr = i4 * 4;
        const int b  = rr >> 11;
        const int t  = rr & 2047;                        // float4 never crosses batch
        const float4* p = (const float4*)Pr + i4;
        const size_t cs = (size_t)(Bdim * Tdim / 4);
        float4 s = p[0];
#pragma unroll
        for (int c = 1; c < 8; ++c) {
            const float4 v = p[c * cs];
            s.x += v.x; s.y += v.y; s.z += v.z; s.w += v.w;
        }
        const float4 mv = *(const float4*)(mask + b * Tdim + t);
        float4 o;
        o.x = mv.x * s.x - 1000.f * (1.f - mv.x);
        o.y = mv.y * s.y - 1000.f * (1.f - mv.y);
        o.z = mv.z * s.z - 1000.f * (1.f - mv.z);
        o.w = mv.w * s.w - 1000.f * (1.f - mv.w);
        *(float4*)(out + (size_t)b * OUTW + Vdim + t) = o;
    }
}

extern "C" void kernel_launch(void* const* d_in, const int* in_sizes, int n_in,
                              void* d_out, int out_size, void* d_ws, size_t ws_size,
                              hipStream_t stream) {
    const float* input_embeds  = (const float*)d_in[0];  // (8,1,512)
    const float* target_embeds = (const float*)d_in[1];  // (8,2048,512)
    const float* input_mask    = (const float*)d_in[2];  // (8,2048)
    const float* w1            = (const float*)d_in[3];  // (512,1024)
    const float* b1            = (const float*)d_in[4];  // (512,)
    const float* w2            = (const float*)d_in[5];  // (512,)
    const float* decoder_w     = (const float*)d_in[6];  // (32000,512)
    float* out = (float*)d_out;

    // ws: qp 16 KB | wt bf16 512x512 (512 KB) | Pd 8x8x32000 f32 (8.19 MB)
    //     | Pr 8x16384 f32 (512 KB)
    float* qp = (float*)d_ws;
    unsigned short* wt = (unsigned short*)((char*)d_ws + 16384);
    float* Pd = (float*)((char*)d_ws + 16384 + 524288);
    float* Pr = Pd + (size_t)8 * Bdim * Vdim;

    prep_kernel<<<WT_BLOCKS + QP_BLOCKS, 256, 0, stream>>>(w1, input_embeds, b1, wt, qp);
    gemm_kernel<<<48 * 32, 256, 0, stream>>>(
        decoder_w, target_embeds, wt, qp, w2, Pd, Pr);
    reduce_kernel<<<RED_DEC_BLOCKS + RED_REP_BLOCKS, 256, 0, stream>>>(
        Pd, Pr, input_mask, out);
}